// Round 1
// baseline (70.716 us; speedup 1.0000x reference)
//
#include <hip/hip_runtime.h>
#include <math.h>

#define N 128
#define HID 512
#define NH (N * HID)                 // 65536
#define SNH ((size_t)N * NH)         // 8388608 elements per s
#define NPAIRS (N * (N + 1) / 2)     // 8256

// workspace layout (float offsets)
#define OFF_SA 0
#define OFF_SB 131072
#define OFF_DG 262144
#define OFF_XR 393216
#define OFF_YC 524288
#define OFF_SV 655360
#define OFF_DB 656384

union F4 { float4 v; float f[4]; };

// ---------------------------------------------------------------------------
// Kernel A: per (s, idx) compute
//   Sa[s][idx][h] = sum_a x[s][a][idx][h]   (row sums of M, M[h,i,j]=x[s,j,i,h])
//   Sb[s][idx][h] = sum_b x[s][idx][b][h]   (col sums of M)
//   Dg[s][idx][h] = x[s][idx][idx][h]       (diag of M)
// block: 512 threads = 4 quarters (q) x 128 h-groups (float4 each)
// ---------------------------------------------------------------------------
__global__ __launch_bounds__(512)
void schur_reduce(const float* __restrict__ x,
                  float* __restrict__ Sa, float* __restrict__ Sb,
                  float* __restrict__ Dg) {
    const int blk = blockIdx.x;           // 0..255
    const int s   = blk >> 7;
    const int idx = blk & 127;
    const int tid = threadIdx.x;
    const int ht  = tid & 127;            // h-group
    const int q   = tid >> 7;             // 0..3
    const int hoff = ht * 4;

    const float* xs   = x + (size_t)s * SNH;
    const float* xrow = xs + (size_t)idx * NH;

    F4 sa; sa.v = make_float4(0.f, 0.f, 0.f, 0.f);
    for (int a = q; a < N; a += 4) {
        F4 v; v.v = *reinterpret_cast<const float4*>(xs + (size_t)a * NH + idx * HID + hoff);
        #pragma unroll
        for (int j = 0; j < 4; ++j) sa.f[j] += v.f[j];
    }
    F4 sb; sb.v = make_float4(0.f, 0.f, 0.f, 0.f);
    for (int b = q; b < N; b += 4) {
        F4 v; v.v = *reinterpret_cast<const float4*>(xrow + b * HID + hoff);
        #pragma unroll
        for (int j = 0; j < 4; ++j) sb.f[j] += v.f[j];
    }

    __shared__ F4 red[4][128];
    red[q][ht] = sa;
    __syncthreads();
    if (q == 0) {
        F4 t;
        #pragma unroll
        for (int j = 0; j < 4; ++j)
            t.f[j] = red[0][ht].f[j] + red[1][ht].f[j] + red[2][ht].f[j] + red[3][ht].f[j];
        *reinterpret_cast<float4*>(Sa + ((size_t)s * N + idx) * HID + hoff) = t.v;
    }
    __syncthreads();
    red[q][ht] = sb;
    __syncthreads();
    if (q == 0) {
        F4 t;
        #pragma unroll
        for (int j = 0; j < 4; ++j)
            t.f[j] = red[0][ht].f[j] + red[1][ht].f[j] + red[2][ht].f[j] + red[3][ht].f[j];
        *reinterpret_cast<float4*>(Sb + ((size_t)s * N + idx) * HID + hoff) = t.v;
        const float4 dv = *reinterpret_cast<const float4*>(xrow + idx * HID + hoff);
        *reinterpret_cast<float4*>(Dg + ((size_t)s * N + idx) * HID + hoff) = dv;
    }
}

// ---------------------------------------------------------------------------
// Kernel B: per (s,h) statistics
//   T = sum_i Sa ; D = sum_i Dg ; s_h = (T-D)/(n(n-1)) ; dbar = D/n
//   r_i = Sa_i - d_i - (n-1)s ; c_i = Sb_i - d_i - (n-1)s
//   xr_i = ((n-1)r_i + c_i)/(n(n-2)) ; yc_i = ((n-1)c_i + r_i)/(n(n-2))
// grid: 8 blocks (s x 4 h-chunks), 128 threads (one h each)
// ---------------------------------------------------------------------------
__global__ __launch_bounds__(128)
void schur_stats(const float* __restrict__ Sa, const float* __restrict__ Sb,
                 const float* __restrict__ Dg,
                 float* __restrict__ Xr, float* __restrict__ Yc,
                 float* __restrict__ Sv, float* __restrict__ Db) {
    const int blk = blockIdx.x;           // 0..7
    const int s   = blk >> 2;
    const int h   = (blk & 3) * 128 + threadIdx.x;
    const size_t base = (size_t)s * N * HID;

    float T = 0.f, D = 0.f;
    for (int i = 0; i < N; ++i) {
        T += Sa[base + (size_t)i * HID + h];
        D += Dg[base + (size_t)i * HID + h];
    }
    const float sh   = (T - D) * (1.0f / (128.0f * 127.0f));
    const float dbar = D * (1.0f / 128.0f);
    Sv[s * HID + h] = sh;
    Db[s * HID + h] = dbar;

    const float k127s = 127.0f * sh;
    const float inv = 1.0f / 16128.0f;    // 1/(n(n-2))
    for (int i = 0; i < N; ++i) {
        const float d = Dg[base + (size_t)i * HID + h];
        const float r = Sa[base + (size_t)i * HID + h] - d - k127s;
        const float c = Sb[base + (size_t)i * HID + h] - d - k127s;
        Xr[base + (size_t)i * HID + h] = (127.0f * r + c) * inv;
        Yc[base + (size_t)i * HID + h] = (127.0f * c + r) * inv;
    }
}

// ---------------------------------------------------------------------------
// Kernel C: output over triangular pairs (a<=b), 128 threads x float4 over h.
//   off-diag, with i=b, j=a (out[s,a,b,h] = Out[h,b,a]):
//     U = x[s,a,b,h] - s - xr[b] - yc[a]   (= R[b,a])
//     V = x[s,b,a,h] - s - xr[a] - yc[b]   (= R[a,b])
//     out[s,a,b,h] = c3 s + c4 xr[b] + c5 yc[a] + al U + be V
//     out[s,b,a,h] = c3 s + c4 xr[a] + c5 yc[b] + al V + be U
//   diag: out[s,a,a,h] = c1 dbar + c2 (x[s,a,a,h] - dbar)
// ---------------------------------------------------------------------------
__global__ __launch_bounds__(128)
void schur_out(const float* __restrict__ x, const float* __restrict__ w,
               const float* __restrict__ iso,
               const float* __restrict__ Xr, const float* __restrict__ Yc,
               const float* __restrict__ Sv, const float* __restrict__ Db,
               float* __restrict__ out) {
    const int blk = blockIdx.x;           // 0 .. 2*NPAIRS-1
    const int s = (blk >= NPAIRS) ? 1 : 0;
    const int p = blk - s * NPAIRS;

    // decode triangular index p -> (a,b), a<=b ; off(a) = a*N - a(a-1)/2
    int a = (int)((257.0f - sqrtf((float)(66049 - 8 * p))) * 0.5f);
    if (a < 0) a = 0;
    if (a > N - 1) a = N - 1;
    #define TRI_OFF(aa) ((aa) * N - (((aa) * ((aa) - 1)) >> 1))
    while (a > 0 && TRI_OFF(a) > p) --a;
    while (TRI_OFF(a + 1) <= p) ++a;
    const int b = a + (p - TRI_OFF(a));

    // coefficients c[j] = sum_i weight[i][j] * iso[i][j]
    float c[7];
    #pragma unroll
    for (int j = 0; j < 7; ++j) {
        float acc = 0.f;
        #pragma unroll
        for (int i = 0; i < 7; ++i) acc += w[i * 7 + j] * iso[i * 7 + j];
        c[j] = acc;
    }
    const float c1 = c[0], c2 = c[1], c3 = c[2], c4 = c[3], c5 = c[4];
    const float al = 0.5f * (c[5] + c[6]);
    const float be = 0.5f * (c[5] - c[6]);

    const int hoff = threadIdx.x * 4;
    const size_t sbase    = (size_t)s * SNH;
    const size_t statbase = (size_t)s * N * HID;

    if (a == b) {
        F4 v;  v.v  = *reinterpret_cast<const float4*>(x + sbase + ((size_t)a * N + a) * HID + hoff);
        F4 db; db.v = *reinterpret_cast<const float4*>(Db + (size_t)s * HID + hoff);
        F4 o;
        #pragma unroll
        for (int j = 0; j < 4; ++j)
            o.f[j] = c1 * db.f[j] + c2 * (v.f[j] - db.f[j]);
        *reinterpret_cast<float4*>(out + sbase + ((size_t)a * N + a) * HID + hoff) = o.v;
        return;
    }

    F4 va;  va.v  = *reinterpret_cast<const float4*>(x + sbase + ((size_t)a * N + b) * HID + hoff);
    F4 vb;  vb.v  = *reinterpret_cast<const float4*>(x + sbase + ((size_t)b * N + a) * HID + hoff);
    F4 xra; xra.v = *reinterpret_cast<const float4*>(Xr + statbase + (size_t)a * HID + hoff);
    F4 xrb; xrb.v = *reinterpret_cast<const float4*>(Xr + statbase + (size_t)b * HID + hoff);
    F4 yca; yca.v = *reinterpret_cast<const float4*>(Yc + statbase + (size_t)a * HID + hoff);
    F4 ycb; ycb.v = *reinterpret_cast<const float4*>(Yc + statbase + (size_t)b * HID + hoff);
    F4 sh;  sh.v  = *reinterpret_cast<const float4*>(Sv + (size_t)s * HID + hoff);

    F4 oab, oba;
    #pragma unroll
    for (int j = 0; j < 4; ++j) {
        const float U = va.f[j] - sh.f[j] - xrb.f[j] - yca.f[j];
        const float V = vb.f[j] - sh.f[j] - xra.f[j] - ycb.f[j];
        oab.f[j] = c3 * sh.f[j] + c4 * xrb.f[j] + c5 * yca.f[j] + al * U + be * V;
        oba.f[j] = c3 * sh.f[j] + c4 * xra.f[j] + c5 * ycb.f[j] + al * V + be * U;
    }
    *reinterpret_cast<float4*>(out + sbase + ((size_t)a * N + b) * HID + hoff) = oab.v;
    *reinterpret_cast<float4*>(out + sbase + ((size_t)b * N + a) * HID + hoff) = oba.v;
}

extern "C" void kernel_launch(void* const* d_in, const int* in_sizes, int n_in,
                              void* d_out, int out_size, void* d_ws, size_t ws_size,
                              hipStream_t stream) {
    const float* x   = (const float*)d_in[0];
    const float* w   = (const float*)d_in[1];
    const float* iso = (const float*)d_in[2];
    float* out = (float*)d_out;
    float* ws  = (float*)d_ws;

    float* Sa = ws + OFF_SA;
    float* Sb = ws + OFF_SB;
    float* Dg = ws + OFF_DG;
    float* Xr = ws + OFF_XR;
    float* Yc = ws + OFF_YC;
    float* Sv = ws + OFF_SV;
    float* Db = ws + OFF_DB;

    schur_reduce<<<2 * N, 512, 0, stream>>>(x, Sa, Sb, Dg);
    schur_stats<<<8, 128, 0, stream>>>(Sa, Sb, Dg, Xr, Yc, Sv, Db);
    schur_out<<<2 * NPAIRS, 128, 0, stream>>>(x, w, iso, Xr, Yc, Sv, Db, out);
}

// Round 3
// 54.577 us; speedup vs baseline: 1.2957x; 1.2957x over previous
//
#include <hip/hip_runtime.h>
#include <math.h>

#define N 128
#define HID 512
#define NH (N * HID)                 // 65536
#define SNH ((size_t)N * NH)         // 8388608 elements per s
#define NPAIRS (N * (N + 1) / 2)     // 8256

// workspace layout (float offsets)
#define OFF_SA 0
#define OFF_SB 131072
#define OFF_DG 262144
#define OFF_XR 393216
#define OFF_YC 524288
#define OFF_SV 655360
#define OFF_DB 656384

typedef float vf4 __attribute__((ext_vector_type(4)));
union F4 { vf4 v; float f[4]; };

// ---------------------------------------------------------------------------
// Kernel A: per (s, idx) compute   (UNCHANGED from R0)
//   Sa[s][idx][h] = sum_a x[s][a][idx][h]   (row sums of M, M[h,i,j]=x[s,j,i,h])
//   Sb[s][idx][h] = sum_b x[s][idx][b][h]   (col sums of M)
//   Dg[s][idx][h] = x[s][idx][idx][h]       (diag of M)
// ---------------------------------------------------------------------------
__global__ __launch_bounds__(512)
void schur_reduce(const float* __restrict__ x,
                  float* __restrict__ Sa, float* __restrict__ Sb,
                  float* __restrict__ Dg) {
    const int blk = blockIdx.x;           // 0..255
    const int s   = blk >> 7;
    const int idx = blk & 127;
    const int tid = threadIdx.x;
    const int ht  = tid & 127;            // h-group
    const int q   = tid >> 7;             // 0..3
    const int hoff = ht * 4;

    const float* xs   = x + (size_t)s * SNH;
    const float* xrow = xs + (size_t)idx * NH;

    F4 sa; sa.v = (vf4)(0.f);
    for (int a = q; a < N; a += 4) {
        F4 v; v.v = *reinterpret_cast<const vf4*>(xs + (size_t)a * NH + idx * HID + hoff);
        #pragma unroll
        for (int j = 0; j < 4; ++j) sa.f[j] += v.f[j];
    }
    F4 sb; sb.v = (vf4)(0.f);
    for (int b = q; b < N; b += 4) {
        F4 v; v.v = *reinterpret_cast<const vf4*>(xrow + b * HID + hoff);
        #pragma unroll
        for (int j = 0; j < 4; ++j) sb.f[j] += v.f[j];
    }

    __shared__ F4 red[4][128];
    red[q][ht] = sa;
    __syncthreads();
    if (q == 0) {
        F4 t;
        #pragma unroll
        for (int j = 0; j < 4; ++j)
            t.f[j] = red[0][ht].f[j] + red[1][ht].f[j] + red[2][ht].f[j] + red[3][ht].f[j];
        *reinterpret_cast<vf4*>(Sa + ((size_t)s * N + idx) * HID + hoff) = t.v;
    }
    __syncthreads();
    red[q][ht] = sb;
    __syncthreads();
    if (q == 0) {
        F4 t;
        #pragma unroll
        for (int j = 0; j < 4; ++j)
            t.f[j] = red[0][ht].f[j] + red[1][ht].f[j] + red[2][ht].f[j] + red[3][ht].f[j];
        *reinterpret_cast<vf4*>(Sb + ((size_t)s * N + idx) * HID + hoff) = t.v;
        const vf4 dv = *reinterpret_cast<const vf4*>(xrow + idx * HID + hoff);
        *reinterpret_cast<vf4*>(Dg + ((size_t)s * N + idx) * HID + hoff) = dv;
    }
}

// ---------------------------------------------------------------------------
// Kernel B: per (s,h) statistics — 32 blocks x 512 threads.
//   block = (s, 32-h chunk); thread = (iq in [0,16), hl in [0,32))
//   phase 1: T,D reduction over i split 16 ways + LDS combine
//   phase 2: Xr/Yc written with 16-way i parallelism
// ---------------------------------------------------------------------------
__global__ __launch_bounds__(512)
void schur_stats(const float* __restrict__ Sa, const float* __restrict__ Sb,
                 const float* __restrict__ Dg,
                 float* __restrict__ Xr, float* __restrict__ Yc,
                 float* __restrict__ Sv, float* __restrict__ Db) {
    const int blk = blockIdx.x;           // 0..31
    const int s   = blk >> 4;
    const int hc  = blk & 15;
    const int t   = threadIdx.x;
    const int iq  = t >> 5;               // 0..15
    const int hl  = t & 31;
    const int h   = hc * 32 + hl;
    const size_t base = (size_t)s * N * HID;

    float T = 0.f, D = 0.f;
    #pragma unroll
    for (int i = iq; i < N; i += 16) {
        T += Sa[base + (size_t)i * HID + h];
        D += Dg[base + (size_t)i * HID + h];
    }

    __shared__ float redT[16][32];
    __shared__ float redD[16][32];
    __shared__ float shS[32];
    redT[iq][hl] = T;
    redD[iq][hl] = D;
    __syncthreads();
    if (iq == 0) {
        float Tt = 0.f, Dd = 0.f;
        #pragma unroll
        for (int q = 0; q < 16; ++q) { Tt += redT[q][hl]; Dd += redD[q][hl]; }
        const float sh   = (Tt - Dd) * (1.0f / 16256.0f);   // /(n(n-1))
        const float dbar = Dd * (1.0f / 128.0f);
        Sv[s * HID + h] = sh;
        Db[s * HID + h] = dbar;
        shS[hl] = sh;
    }
    __syncthreads();

    const float sh    = shS[hl];
    const float k127s = 127.0f * sh;
    const float inv   = 1.0f / 16128.0f;  // 1/(n(n-2))
    #pragma unroll
    for (int i = iq; i < N; i += 16) {
        const size_t o = base + (size_t)i * HID + h;
        const float d = Dg[o];
        const float r = Sa[o] - d - k127s;
        const float c = Sb[o] - d - k127s;
        Xr[o] = (127.0f * r + c) * inv;
        Yc[o] = (127.0f * c + r) * inv;
    }
}

// ---------------------------------------------------------------------------
// Kernel C: output over triangular pairs — 2064 blocks x 256 threads,
// each block handles 8 consecutive pairs (2 slots x 4 iterations).
// Nontemporal stores for out (never re-read; keep x in L3).
// ---------------------------------------------------------------------------
__global__ __launch_bounds__(256)
void schur_out(const float* __restrict__ x, const float* __restrict__ w,
               const float* __restrict__ iso,
               const float* __restrict__ Xr, const float* __restrict__ Yc,
               const float* __restrict__ Sv, const float* __restrict__ Db,
               float* __restrict__ out) {
    const int t  = threadIdx.x;
    const int k  = t >> 7;                // pair slot 0/1
    const int ht = t & 127;
    const int hoff = ht * 4;

    // coefficients c[j] = sum_i weight[i][j] * iso[i][j]
    float c[7];
    #pragma unroll
    for (int j = 0; j < 7; ++j) {
        float acc = 0.f;
        #pragma unroll
        for (int i = 0; i < 7; ++i) acc += w[i * 7 + j] * iso[i * 7 + j];
        c[j] = acc;
    }
    const float c1 = c[0], c2 = c[1], c3 = c[2], c4 = c[3], c5 = c[4];
    const float al = 0.5f * (c[5] + c[6]);
    const float be = 0.5f * (c[5] - c[6]);

    const int pg0 = blockIdx.x * 8;

    #define TRI_OFF(aa) ((aa) * N - (((aa) * ((aa) - 1)) >> 1))
    #pragma unroll
    for (int it = 0; it < 4; ++it) {
        const int pg = pg0 + it * 2 + k;          // global pair id, < 16512
        const int s  = (pg >= NPAIRS) ? 1 : 0;
        const int p  = pg - s * NPAIRS;

        int a = (int)((257.0f - sqrtf((float)(66049 - 8 * p))) * 0.5f);
        if (a < 0) a = 0;
        if (a > N - 1) a = N - 1;
        while (a > 0 && TRI_OFF(a) > p) --a;
        while (TRI_OFF(a + 1) <= p) ++a;
        const int b = a + (p - TRI_OFF(a));

        const size_t sbase    = (size_t)s * SNH;
        const size_t statbase = (size_t)s * N * HID;

        if (a == b) {
            F4 v;  v.v  = *reinterpret_cast<const vf4*>(x + sbase + ((size_t)a * N + a) * HID + hoff);
            F4 db; db.v = *reinterpret_cast<const vf4*>(Db + (size_t)s * HID + hoff);
            F4 o;
            #pragma unroll
            for (int j = 0; j < 4; ++j)
                o.f[j] = c1 * db.f[j] + c2 * (v.f[j] - db.f[j]);
            __builtin_nontemporal_store(o.v,
                reinterpret_cast<vf4*>(out + sbase + ((size_t)a * N + a) * HID + hoff));
            continue;
        }

        F4 va;  va.v  = *reinterpret_cast<const vf4*>(x + sbase + ((size_t)a * N + b) * HID + hoff);
        F4 vb;  vb.v  = *reinterpret_cast<const vf4*>(x + sbase + ((size_t)b * N + a) * HID + hoff);
        F4 xra; xra.v = *reinterpret_cast<const vf4*>(Xr + statbase + (size_t)a * HID + hoff);
        F4 xrb; xrb.v = *reinterpret_cast<const vf4*>(Xr + statbase + (size_t)b * HID + hoff);
        F4 yca; yca.v = *reinterpret_cast<const vf4*>(Yc + statbase + (size_t)a * HID + hoff);
        F4 ycb; ycb.v = *reinterpret_cast<const vf4*>(Yc + statbase + (size_t)b * HID + hoff);
        F4 sh;  sh.v  = *reinterpret_cast<const vf4*>(Sv + (size_t)s * HID + hoff);

        F4 oab, oba;
        #pragma unroll
        for (int j = 0; j < 4; ++j) {
            const float U = va.f[j] - sh.f[j] - xrb.f[j] - yca.f[j];
            const float V = vb.f[j] - sh.f[j] - xra.f[j] - ycb.f[j];
            oab.f[j] = c3 * sh.f[j] + c4 * xrb.f[j] + c5 * yca.f[j] + al * U + be * V;
            oba.f[j] = c3 * sh.f[j] + c4 * xra.f[j] + c5 * ycb.f[j] + al * V + be * U;
        }
        __builtin_nontemporal_store(oab.v,
            reinterpret_cast<vf4*>(out + sbase + ((size_t)a * N + b) * HID + hoff));
        __builtin_nontemporal_store(oba.v,
            reinterpret_cast<vf4*>(out + sbase + ((size_t)b * N + a) * HID + hoff));
    }
}

extern "C" void kernel_launch(void* const* d_in, const int* in_sizes, int n_in,
                              void* d_out, int out_size, void* d_ws, size_t ws_size,
                              hipStream_t stream) {
    const float* x   = (const float*)d_in[0];
    const float* w   = (const float*)d_in[1];
    const float* iso = (const float*)d_in[2];
    float* out = (float*)d_out;
    float* ws  = (float*)d_ws;

    float* Sa = ws + OFF_SA;
    float* Sb = ws + OFF_SB;
    float* Dg = ws + OFF_DG;
    float* Xr = ws + OFF_XR;
    float* Yc = ws + OFF_YC;
    float* Sv = ws + OFF_SV;
    float* Db = ws + OFF_DB;

    schur_reduce<<<2 * N, 512, 0, stream>>>(x, Sa, Sb, Dg);
    schur_stats<<<32, 512, 0, stream>>>(Sa, Sb, Dg, Xr, Yc, Sv, Db);
    schur_out<<<(2 * NPAIRS) / 8, 256, 0, stream>>>(x, w, iso, Xr, Yc, Sv, Db, out);
}

// Round 4
// 53.616 us; speedup vs baseline: 1.3189x; 1.0179x over previous
//
#include <hip/hip_runtime.h>
#include <math.h>

#define N 128
#define HID 512
#define NH (N * HID)                 // 65536
#define SNH ((size_t)N * NH)         // 8388608 elements per s
#define NPAIRS (N * (N + 1) / 2)     // 8256

// workspace layout (float offsets)
#define OFF_SA 0
#define OFF_SB 131072
#define OFF_DG 262144
#define OFF_XR 393216
#define OFF_YC 524288
#define OFF_SV 655360
#define OFF_DB 656384

typedef float vf4 __attribute__((ext_vector_type(4)));
union F4 { vf4 v; float f[4]; };

// ---------------------------------------------------------------------------
// Kernel A: per (s, idx) sums — wave-specialized 1024-thread blocks.
//   waves 0-7  (half=0): Sa[s][idx][h] = sum_a x[s][a][idx][h]  (col pass)
//   waves 8-15 (half=1): Sb[s][idx][h] = sum_b x[s][idx][b][h]  (row pass)
//                        Dg[s][idx][h] = x[s][idx][idx][h]
//   Each half: 128 h-groups x 4 quarters; quarter q sums a in [q*32,q*32+32)
//   with 4 independent accumulators (4 loads in flight per thread).
// ---------------------------------------------------------------------------
__global__ __launch_bounds__(1024)
void schur_reduce(const float* __restrict__ x,
                  float* __restrict__ Sa, float* __restrict__ Sb,
                  float* __restrict__ Dg) {
    const int blk  = blockIdx.x;          // 0..255
    const int s    = blk >> 7;
    const int idx  = blk & 127;
    const int tid  = threadIdx.x;
    const int half = tid >> 9;            // 0: col pass, 1: row pass
    const int t    = tid & 511;
    const int ht   = t & 127;             // h-group
    const int q    = t >> 7;              // 0..3
    const int hoff = ht * 4;

    const float* xs   = x + (size_t)s * SNH;
    const float* xrow = xs + (size_t)idx * NH;

    __shared__ F4 redA[4][128];
    __shared__ F4 redB[4][128];

    F4 dv;
    if (half == 0) {
        F4 s0, s1, s2, s3;
        s0.v = (vf4)(0.f); s1.v = (vf4)(0.f); s2.v = (vf4)(0.f); s3.v = (vf4)(0.f);
        const float* p = xs + (size_t)(q * 32) * NH + idx * HID + hoff;
        for (int a = 0; a < 32; a += 4) {
            F4 v0; v0.v = *reinterpret_cast<const vf4*>(p + (size_t)(a + 0) * NH);
            F4 v1; v1.v = *reinterpret_cast<const vf4*>(p + (size_t)(a + 1) * NH);
            F4 v2; v2.v = *reinterpret_cast<const vf4*>(p + (size_t)(a + 2) * NH);
            F4 v3; v3.v = *reinterpret_cast<const vf4*>(p + (size_t)(a + 3) * NH);
            s0.v += v0.v; s1.v += v1.v; s2.v += v2.v; s3.v += v3.v;
        }
        s0.v = (s0.v + s1.v) + (s2.v + s3.v);
        redA[q][ht] = s0;
    } else {
        F4 s0, s1, s2, s3;
        s0.v = (vf4)(0.f); s1.v = (vf4)(0.f); s2.v = (vf4)(0.f); s3.v = (vf4)(0.f);
        const float* p = xrow + q * 32 * HID + hoff;
        for (int b = 0; b < 32; b += 4) {
            F4 v0; v0.v = *reinterpret_cast<const vf4*>(p + (b + 0) * HID);
            F4 v1; v1.v = *reinterpret_cast<const vf4*>(p + (b + 1) * HID);
            F4 v2; v2.v = *reinterpret_cast<const vf4*>(p + (b + 2) * HID);
            F4 v3; v3.v = *reinterpret_cast<const vf4*>(p + (b + 3) * HID);
            s0.v += v0.v; s1.v += v1.v; s2.v += v2.v; s3.v += v3.v;
        }
        s0.v = (s0.v + s1.v) + (s2.v + s3.v);
        redB[q][ht] = s0;
        if (q == 0)
            dv.v = *reinterpret_cast<const vf4*>(xrow + idx * HID + hoff);
    }
    __syncthreads();

    if (q == 0) {
        if (half == 0) {
            F4 tt;
            tt.v = (redA[0][ht].v + redA[1][ht].v) + (redA[2][ht].v + redA[3][ht].v);
            *reinterpret_cast<vf4*>(Sa + ((size_t)s * N + idx) * HID + hoff) = tt.v;
        } else {
            F4 tt;
            tt.v = (redB[0][ht].v + redB[1][ht].v) + (redB[2][ht].v + redB[3][ht].v);
            *reinterpret_cast<vf4*>(Sb + ((size_t)s * N + idx) * HID + hoff) = tt.v;
            *reinterpret_cast<vf4*>(Dg + ((size_t)s * N + idx) * HID + hoff) = dv.v;
        }
    }
}

// ---------------------------------------------------------------------------
// Kernel B: per (s,h) statistics — 32 blocks x 512 threads.  (unchanged)
// ---------------------------------------------------------------------------
__global__ __launch_bounds__(512)
void schur_stats(const float* __restrict__ Sa, const float* __restrict__ Sb,
                 const float* __restrict__ Dg,
                 float* __restrict__ Xr, float* __restrict__ Yc,
                 float* __restrict__ Sv, float* __restrict__ Db) {
    const int blk = blockIdx.x;           // 0..31
    const int s   = blk >> 4;
    const int hc  = blk & 15;
    const int t   = threadIdx.x;
    const int iq  = t >> 5;               // 0..15
    const int hl  = t & 31;
    const int h   = hc * 32 + hl;
    const size_t base = (size_t)s * N * HID;

    float T = 0.f, D = 0.f;
    #pragma unroll
    for (int i = iq; i < N; i += 16) {
        T += Sa[base + (size_t)i * HID + h];
        D += Dg[base + (size_t)i * HID + h];
    }

    __shared__ float redT[16][32];
    __shared__ float redD[16][32];
    __shared__ float shS[32];
    redT[iq][hl] = T;
    redD[iq][hl] = D;
    __syncthreads();
    if (iq == 0) {
        float Tt = 0.f, Dd = 0.f;
        #pragma unroll
        for (int q = 0; q < 16; ++q) { Tt += redT[q][hl]; Dd += redD[q][hl]; }
        const float sh   = (Tt - Dd) * (1.0f / 16256.0f);   // /(n(n-1))
        const float dbar = Dd * (1.0f / 128.0f);
        Sv[s * HID + h] = sh;
        Db[s * HID + h] = dbar;
        shS[hl] = sh;
    }
    __syncthreads();

    const float sh    = shS[hl];
    const float k127s = 127.0f * sh;
    const float inv   = 1.0f / 16128.0f;  // 1/(n(n-2))
    #pragma unroll
    for (int i = iq; i < N; i += 16) {
        const size_t o = base + (size_t)i * HID + h;
        const float d = Dg[o];
        const float r = Sa[o] - d - k127s;
        const float c = Sb[o] - d - k127s;
        Xr[o] = (127.0f * r + c) * inv;
        Yc[o] = (127.0f * c + r) * inv;
    }
}

// ---------------------------------------------------------------------------
// Kernel C: output over triangular pairs — 2064 blocks x 256 threads,
// 8 consecutive pairs per block; nontemporal stores.  (unchanged)
// ---------------------------------------------------------------------------
__global__ __launch_bounds__(256)
void schur_out(const float* __restrict__ x, const float* __restrict__ w,
               const float* __restrict__ iso,
               const float* __restrict__ Xr, const float* __restrict__ Yc,
               const float* __restrict__ Sv, const float* __restrict__ Db,
               float* __restrict__ out) {
    const int t  = threadIdx.x;
    const int k  = t >> 7;                // pair slot 0/1
    const int ht = t & 127;
    const int hoff = ht * 4;

    float c[7];
    #pragma unroll
    for (int j = 0; j < 7; ++j) {
        float acc = 0.f;
        #pragma unroll
        for (int i = 0; i < 7; ++i) acc += w[i * 7 + j] * iso[i * 7 + j];
        c[j] = acc;
    }
    const float c1 = c[0], c2 = c[1], c3 = c[2], c4 = c[3], c5 = c[4];
    const float al = 0.5f * (c[5] + c[6]);
    const float be = 0.5f * (c[5] - c[6]);

    const int pg0 = blockIdx.x * 8;

    #define TRI_OFF(aa) ((aa) * N - (((aa) * ((aa) - 1)) >> 1))
    #pragma unroll
    for (int it = 0; it < 4; ++it) {
        const int pg = pg0 + it * 2 + k;          // global pair id, < 16512
        const int s  = (pg >= NPAIRS) ? 1 : 0;
        const int p  = pg - s * NPAIRS;

        int a = (int)((257.0f - sqrtf((float)(66049 - 8 * p))) * 0.5f);
        if (a < 0) a = 0;
        if (a > N - 1) a = N - 1;
        while (a > 0 && TRI_OFF(a) > p) --a;
        while (TRI_OFF(a + 1) <= p) ++a;
        const int b = a + (p - TRI_OFF(a));

        const size_t sbase    = (size_t)s * SNH;
        const size_t statbase = (size_t)s * N * HID;

        if (a == b) {
            F4 v;  v.v  = *reinterpret_cast<const vf4*>(x + sbase + ((size_t)a * N + a) * HID + hoff);
            F4 db; db.v = *reinterpret_cast<const vf4*>(Db + (size_t)s * HID + hoff);
            F4 o;
            #pragma unroll
            for (int j = 0; j < 4; ++j)
                o.f[j] = c1 * db.f[j] + c2 * (v.f[j] - db.f[j]);
            __builtin_nontemporal_store(o.v,
                reinterpret_cast<vf4*>(out + sbase + ((size_t)a * N + a) * HID + hoff));
            continue;
        }

        F4 va;  va.v  = *reinterpret_cast<const vf4*>(x + sbase + ((size_t)a * N + b) * HID + hoff);
        F4 vb;  vb.v  = *reinterpret_cast<const vf4*>(x + sbase + ((size_t)b * N + a) * HID + hoff);
        F4 xra; xra.v = *reinterpret_cast<const vf4*>(Xr + statbase + (size_t)a * HID + hoff);
        F4 xrb; xrb.v = *reinterpret_cast<const vf4*>(Xr + statbase + (size_t)b * HID + hoff);
        F4 yca; yca.v = *reinterpret_cast<const vf4*>(Yc + statbase + (size_t)a * HID + hoff);
        F4 ycb; ycb.v = *reinterpret_cast<const vf4*>(Yc + statbase + (size_t)b * HID + hoff);
        F4 sh;  sh.v  = *reinterpret_cast<const vf4*>(Sv + (size_t)s * HID + hoff);

        F4 oab, oba;
        #pragma unroll
        for (int j = 0; j < 4; ++j) {
            const float U = va.f[j] - sh.f[j] - xrb.f[j] - yca.f[j];
            const float V = vb.f[j] - sh.f[j] - xra.f[j] - ycb.f[j];
            oab.f[j] = c3 * sh.f[j] + c4 * xrb.f[j] + c5 * yca.f[j] + al * U + be * V;
            oba.f[j] = c3 * sh.f[j] + c4 * xra.f[j] + c5 * ycb.f[j] + al * V + be * U;
        }
        __builtin_nontemporal_store(oab.v,
            reinterpret_cast<vf4*>(out + sbase + ((size_t)a * N + b) * HID + hoff));
        __builtin_nontemporal_store(oba.v,
            reinterpret_cast<vf4*>(out + sbase + ((size_t)b * N + a) * HID + hoff));
    }
}

extern "C" void kernel_launch(void* const* d_in, const int* in_sizes, int n_in,
                              void* d_out, int out_size, void* d_ws, size_t ws_size,
                              hipStream_t stream) {
    const float* x   = (const float*)d_in[0];
    const float* w   = (const float*)d_in[1];
    const float* iso = (const float*)d_in[2];
    float* out = (float*)d_out;
    float* ws  = (float*)d_ws;

    float* Sa = ws + OFF_SA;
    float* Sb = ws + OFF_SB;
    float* Dg = ws + OFF_DG;
    float* Xr = ws + OFF_XR;
    float* Yc = ws + OFF_YC;
    float* Sv = ws + OFF_SV;
    float* Db = ws + OFF_DB;

    schur_reduce<<<2 * N, 1024, 0, stream>>>(x, Sa, Sb, Dg);
    schur_stats<<<32, 512, 0, stream>>>(Sa, Sb, Dg, Xr, Yc, Sv, Db);
    schur_out<<<(2 * NPAIRS) / 8, 256, 0, stream>>>(x, w, iso, Xr, Yc, Sv, Db, out);
}

// Round 5
// 52.133 us; speedup vs baseline: 1.3564x; 1.0284x over previous
//
#include <hip/hip_runtime.h>
#include <math.h>

#define N 128
#define HID 512
#define NH (N * HID)                 // 65536
#define SNH ((size_t)N * NH)         // 8388608 elements per s
#define NPAIRS (N * (N + 1) / 2)     // 8256

// workspace layout (float offsets); ws proven >= 256 MiB by harness fills
#define OFF_PSR 0                    // PSrow [2][16][128][512]
#define OFF_PSC 2097152              // PScol [2][16][128][512]
#define OFF_DG  4194304              // Dg    [2][128][512]
#define OFF_XR  4325376
#define OFF_YC  4456448
#define OFF_SV  4587520
#define OFF_DB  4588544

typedef float vf4 __attribute__((ext_vector_type(4)));
union F4 { vf4 v; float f[4]; };

// ---------------------------------------------------------------------------
// Kernel A': one-pass 2D-tiled partial sums. Each block owns an 8x8 (a,b)
// tile and reads its 128 KiB of x EXACTLY ONCE.
//   PSrow[s][br][a][h] = sum_{b in br-tile} x[s][a][b][h]
//   PScol[s][ar][b][h] = sum_{a in ar-tile} x[s][a][b][h]
//   Dg[s][a][h]        = x[s][a][a][h]      (written by diagonal tiles)
// grid: 512 blocks = s(2) x ar(16) x br(16); 512 threads = hg(128) x qd(4).
// Thread (hg,qd): rows {qd*2, qd*2+1} of the tile, all 8 cols, one float4 of h.
// ---------------------------------------------------------------------------
__global__ __launch_bounds__(512)
void schur_tile(const float* __restrict__ x,
                float* __restrict__ PSrow, float* __restrict__ PScol,
                float* __restrict__ Dg) {
    const int bi = blockIdx.x;
    const int s  = bi >> 8;
    const int ar = (bi >> 4) & 15;
    const int br = bi & 15;
    const int tid = threadIdx.x;
    const int hg  = tid & 127;
    const int qd  = tid >> 7;             // 0..3
    const int hoff = hg * 4;
    const bool diag = (ar == br);

    const float* tbase = x + (size_t)s * SNH + (size_t)(ar * 8) * NH
                           + (br * 8) * HID + hoff;

    F4 colacc[8];
    #pragma unroll
    for (int b = 0; b < 8; ++b) colacc[b].v = (vf4)(0.f);

    __shared__ F4 red[4][8][128];         // 64 KiB

    #pragma unroll
    for (int ra = 0; ra < 2; ++ra) {
        const int al = qd * 2 + ra;       // local row 0..7
        const float* rp = tbase + (size_t)al * NH;
        F4 rowacc; rowacc.v = (vf4)(0.f);
        F4 dgv;    dgv.v    = (vf4)(0.f);
        #pragma unroll
        for (int b = 0; b < 8; ++b) {
            F4 v; v.v = *reinterpret_cast<const vf4*>(rp + b * HID);
            rowacc.v += v.v;
            colacc[b].v += v.v;
            if (diag && b == al) dgv = v;
        }
        const int a = ar * 8 + al;
        *reinterpret_cast<vf4*>(PSrow + (((size_t)(s * 16 + br) * 128 + a) * 512 + hoff)) = rowacc.v;
        if (diag)
            *reinterpret_cast<vf4*>(Dg + (((size_t)s * 128 + a) * 512 + hoff)) = dgv.v;
    }

    #pragma unroll
    for (int b = 0; b < 8; ++b) red[qd][b][hg] = colacc[b];
    __syncthreads();

    #pragma unroll
    for (int k = 0; k < 2; ++k) {
        const int b = qd * 2 + k;
        F4 t;
        t.v = (red[0][b][hg].v + red[1][b][hg].v) + (red[2][b][hg].v + red[3][b][hg].v);
        const int gb = br * 8 + b;
        *reinterpret_cast<vf4*>(PScol + (((size_t)(s * 16 + ar) * 128 + gb) * 512 + hoff)) = t.v;
    }
}

// ---------------------------------------------------------------------------
// Kernel B': reduce PS partials + per-(s,h) statistics, one pass.
// grid: 32 blocks (s x 16 h-chunks), 512 threads (iq in [0,16) x hl in [0,32)).
// Each thread owns 8 i-values (i = iq + k*16), reduces 16 partials for each,
// keeps sa/sb/d in registers, LDS-reduces T,D, then writes Xr/Yc/Sv/Db.
// ---------------------------------------------------------------------------
__global__ __launch_bounds__(512)
void schur_stats(const float* __restrict__ PSrow, const float* __restrict__ PScol,
                 const float* __restrict__ Dg,
                 float* __restrict__ Xr, float* __restrict__ Yc,
                 float* __restrict__ Sv, float* __restrict__ Db) {
    const int blk = blockIdx.x;           // 0..31
    const int s   = blk >> 4;
    const int hc  = blk & 15;
    const int t   = threadIdx.x;
    const int iq  = t >> 5;               // 0..15
    const int hl  = t & 31;
    const int h   = hc * 32 + hl;

    float sa8[8], sb8[8], d8[8];
    float T = 0.f, D = 0.f;
    #pragma unroll
    for (int k = 0; k < 8; ++k) {
        const int i = iq + k * 16;
        float sa = 0.f, sb = 0.f;
        #pragma unroll
        for (int tt = 0; tt < 16; ++tt) {
            sa += PScol[((size_t)(s * 16 + tt) * 128 + i) * 512 + h];
            sb += PSrow[((size_t)(s * 16 + tt) * 128 + i) * 512 + h];
        }
        const float d = Dg[((size_t)s * 128 + i) * 512 + h];
        sa8[k] = sa; sb8[k] = sb; d8[k] = d;
        T += sa; D += d;
    }

    __shared__ float redT[16][32];
    __shared__ float redD[16][32];
    __shared__ float shS[32];
    redT[iq][hl] = T;
    redD[iq][hl] = D;
    __syncthreads();
    if (iq == 0) {
        float Tt = 0.f, Dd = 0.f;
        #pragma unroll
        for (int q = 0; q < 16; ++q) { Tt += redT[q][hl]; Dd += redD[q][hl]; }
        const float sh   = (Tt - Dd) * (1.0f / 16256.0f);   // /(n(n-1))
        const float dbar = Dd * (1.0f / 128.0f);
        Sv[s * HID + h] = sh;
        Db[s * HID + h] = dbar;
        shS[hl] = sh;
    }
    __syncthreads();

    const float sh    = shS[hl];
    const float k127s = 127.0f * sh;
    const float inv   = 1.0f / 16128.0f;  // 1/(n(n-2))
    const size_t base = (size_t)s * N * HID;
    #pragma unroll
    for (int k = 0; k < 8; ++k) {
        const int i = iq + k * 16;
        const float d = d8[k];
        const float r = sa8[k] - d - k127s;
        const float c = sb8[k] - d - k127s;
        Xr[base + (size_t)i * HID + h] = (127.0f * r + c) * inv;
        Yc[base + (size_t)i * HID + h] = (127.0f * c + r) * inv;
    }
}

// ---------------------------------------------------------------------------
// Kernel C: output over triangular pairs — 2064 blocks x 256 threads,
// 8 consecutive pairs per block; nontemporal stores.  (unchanged from R4)
// ---------------------------------------------------------------------------
__global__ __launch_bounds__(256)
void schur_out(const float* __restrict__ x, const float* __restrict__ w,
               const float* __restrict__ iso,
               const float* __restrict__ Xr, const float* __restrict__ Yc,
               const float* __restrict__ Sv, const float* __restrict__ Db,
               float* __restrict__ out) {
    const int t  = threadIdx.x;
    const int k  = t >> 7;                // pair slot 0/1
    const int ht = t & 127;
    const int hoff = ht * 4;

    float c[7];
    #pragma unroll
    for (int j = 0; j < 7; ++j) {
        float acc = 0.f;
        #pragma unroll
        for (int i = 0; i < 7; ++i) acc += w[i * 7 + j] * iso[i * 7 + j];
        c[j] = acc;
    }
    const float c1 = c[0], c2 = c[1], c3 = c[2], c4 = c[3], c5 = c[4];
    const float al = 0.5f * (c[5] + c[6]);
    const float be = 0.5f * (c[5] - c[6]);

    const int pg0 = blockIdx.x * 8;

    #define TRI_OFF(aa) ((aa) * N - (((aa) * ((aa) - 1)) >> 1))
    #pragma unroll
    for (int it = 0; it < 4; ++it) {
        const int pg = pg0 + it * 2 + k;          // global pair id, < 16512
        const int s  = (pg >= NPAIRS) ? 1 : 0;
        const int p  = pg - s * NPAIRS;

        int a = (int)((257.0f - sqrtf((float)(66049 - 8 * p))) * 0.5f);
        if (a < 0) a = 0;
        if (a > N - 1) a = N - 1;
        while (a > 0 && TRI_OFF(a) > p) --a;
        while (TRI_OFF(a + 1) <= p) ++a;
        const int b = a + (p - TRI_OFF(a));

        const size_t sbase    = (size_t)s * SNH;
        const size_t statbase = (size_t)s * N * HID;

        if (a == b) {
            F4 v;  v.v  = *reinterpret_cast<const vf4*>(x + sbase + ((size_t)a * N + a) * HID + hoff);
            F4 db; db.v = *reinterpret_cast<const vf4*>(Db + (size_t)s * HID + hoff);
            F4 o;
            #pragma unroll
            for (int j = 0; j < 4; ++j)
                o.f[j] = c1 * db.f[j] + c2 * (v.f[j] - db.f[j]);
            __builtin_nontemporal_store(o.v,
                reinterpret_cast<vf4*>(out + sbase + ((size_t)a * N + a) * HID + hoff));
            continue;
        }

        F4 va;  va.v  = *reinterpret_cast<const vf4*>(x + sbase + ((size_t)a * N + b) * HID + hoff);
        F4 vb;  vb.v  = *reinterpret_cast<const vf4*>(x + sbase + ((size_t)b * N + a) * HID + hoff);
        F4 xra; xra.v = *reinterpret_cast<const vf4*>(Xr + statbase + (size_t)a * HID + hoff);
        F4 xrb; xrb.v = *reinterpret_cast<const vf4*>(Xr + statbase + (size_t)b * HID + hoff);
        F4 yca; yca.v = *reinterpret_cast<const vf4*>(Yc + statbase + (size_t)a * HID + hoff);
        F4 ycb; ycb.v = *reinterpret_cast<const vf4*>(Yc + statbase + (size_t)b * HID + hoff);
        F4 sh;  sh.v  = *reinterpret_cast<const vf4*>(Sv + (size_t)s * HID + hoff);

        F4 oab, oba;
        #pragma unroll
        for (int j = 0; j < 4; ++j) {
            const float U = va.f[j] - sh.f[j] - xrb.f[j] - yca.f[j];
            const float V = vb.f[j] - sh.f[j] - xra.f[j] - ycb.f[j];
            oab.f[j] = c3 * sh.f[j] + c4 * xrb.f[j] + c5 * yca.f[j] + al * U + be * V;
            oba.f[j] = c3 * sh.f[j] + c4 * xra.f[j] + c5 * ycb.f[j] + al * V + be * U;
        }
        __builtin_nontemporal_store(oab.v,
            reinterpret_cast<vf4*>(out + sbase + ((size_t)a * N + b) * HID + hoff));
        __builtin_nontemporal_store(oba.v,
            reinterpret_cast<vf4*>(out + sbase + ((size_t)b * N + a) * HID + hoff));
    }
}

extern "C" void kernel_launch(void* const* d_in, const int* in_sizes, int n_in,
                              void* d_out, int out_size, void* d_ws, size_t ws_size,
                              hipStream_t stream) {
    const float* x   = (const float*)d_in[0];
    const float* w   = (const float*)d_in[1];
    const float* iso = (const float*)d_in[2];
    float* out = (float*)d_out;
    float* ws  = (float*)d_ws;

    float* PSrow = ws + OFF_PSR;
    float* PScol = ws + OFF_PSC;
    float* Dg    = ws + OFF_DG;
    float* Xr    = ws + OFF_XR;
    float* Yc    = ws + OFF_YC;
    float* Sv    = ws + OFF_SV;
    float* Db    = ws + OFF_DB;

    schur_tile<<<512, 512, 0, stream>>>(x, PSrow, PScol, Dg);
    schur_stats<<<32, 512, 0, stream>>>(PSrow, PScol, Dg, Xr, Yc, Sv, Db);
    schur_out<<<(2 * NPAIRS) / 8, 256, 0, stream>>>(x, w, iso, Xr, Yc, Sv, Db, out);
}